// Round 16
// baseline (312.941 us; speedup 1.0000x reference)
//
#include <hip/hip_runtime.h>

#define CDIV(a,b) (((a)+(b)-1)/(b))
#define NPB 256     // nodes per bucket; bucket(d) = d >> 8
#define PCHUNK 2048 // edges per partition chunk
#define WSB 12      // wsplit blocks

typedef __attribute__((ext_vector_type(8))) short bf16x8;
typedef __attribute__((ext_vector_type(8))) unsigned short u16x8;
typedef __attribute__((ext_vector_type(4))) float f32x4;

__device__ __forceinline__ unsigned short f2bf(float x){
    unsigned int u = __float_as_uint(x);
    unsigned int r = u + 0x7FFFu + ((u >> 16) & 1u);   // RNE
    return (unsigned short)(r >> 16);
}
__device__ __forceinline__ float bf2f(unsigned short h){
    return __uint_as_float(((unsigned int)h) << 16);
}

// ---------------- gemm layer-1 body (K=128, no dinv) ----------------
__device__ __forceinline__ void gemm1_body(int gb,
                                           const float* __restrict__ XU, const float* __restrict__ XI,
                                           const unsigned short* __restrict__ Bhi, const unsigned short* __restrict__ Blo,
                                           unsigned short* __restrict__ GU, unsigned short* __restrict__ GI,
                                           int NU, int NI, int gbU){
    const int type = (gb >= gbU);
    const int blk  = type ? gb - gbU : gb;
    const float* X = type ? XI : XU;
    unsigned short* G = type ? GI : GU;
    const int N    = type ? NI : NU;
    const unsigned short* Bh = Bhi + (type ? 8192 : 0);
    const unsigned short* Bl = Blo + (type ? 8192 : 0);

    const int l = threadIdx.x & 63;
    const int w = threadIdx.x >> 6;
    const int row0 = blk*64 + w*16;
    if (row0 >= N) return;

    f32x4 acc[4];
    #pragma unroll
    for (int ct = 0; ct < 4; ++ct) acc[ct] = (f32x4){0.f,0.f,0.f,0.f};

    const int rA = row0 + (l & 15);
    const int kg = (l >> 4) * 8;
    const bool rowok = (rA < N);
    const float* xrow = X + (size_t)rA * 128;

    #pragma unroll
    for (int ks = 0; ks < 4; ++ks){
        float xv[8];
        if (rowok){
            const float4 a = *(const float4*)(xrow + ks*32 + kg);
            const float4 b = *(const float4*)(xrow + ks*32 + kg + 4);
            xv[0]=a.x; xv[1]=a.y; xv[2]=a.z; xv[3]=a.w;
            xv[4]=b.x; xv[5]=b.y; xv[6]=b.z; xv[7]=b.w;
        } else {
            #pragma unroll
            for (int j = 0; j < 8; ++j) xv[j] = 0.f;
        }
        bf16x8 ahi, alo;
        #pragma unroll
        for (int j = 0; j < 8; ++j){
            const unsigned short h = f2bf(xv[j]);
            ahi[j] = (short)h;
            alo[j] = (short)f2bf(xv[j] - bf2f(h));
        }
        #pragma unroll
        for (int ct = 0; ct < 4; ++ct){
            const bf16x8 bhi = *(const bf16x8*)(Bh + ((size_t)(ks*4 + ct)*64 + l)*8);
            const bf16x8 blo = *(const bf16x8*)(Bl + ((size_t)(ks*4 + ct)*64 + l)*8);
            acc[ct] = __builtin_amdgcn_mfma_f32_16x16x32_bf16(ahi, bhi, acc[ct], 0, 0, 0);
            acc[ct] = __builtin_amdgcn_mfma_f32_16x16x32_bf16(alo, bhi, acc[ct], 0, 0, 0);
            acc[ct] = __builtin_amdgcn_mfma_f32_16x16x32_bf16(ahi, blo, acc[ct], 0, 0, 0);
        }
    }

    const int orow0 = row0 + (l >> 4)*4;
    const int ocol  = l & 15;
    #pragma unroll
    for (int r = 0; r < 4; ++r){
        const int orow = orow0 + r;
        if (orow < N){
            #pragma unroll
            for (int ct = 0; ct < 4; ++ct)
                G[(size_t)orow*64 + ct*16 + ocol] = f2bf(acc[ct][r]);
        }
    }
}

#define GEMM_TAIL(taskTot) \
    if ((int)blockIdx.x >= (taskTot)){ \
        gemm1_body(goff + blockIdx.x - (taskTot), XU, XI, Bhi, Blo, GU, GI, NU, NI, gbU); \
        return; \
    }

// ---------------- link1: wsplit (blocks 0..WSB) + chist ----------------
__global__ __launch_bounds__(256) void hg_link1(const float* __restrict__ W1u, const float* __restrict__ W1i,
                                                const float* __restrict__ W2u, const float* __restrict__ W2i,
                                                unsigned short* __restrict__ Bhi, unsigned short* __restrict__ Blo,
                                                const int* __restrict__ eiU, const int* __restrict__ eiI,
                                                int* __restrict__ chU, int* __restrict__ chI,
                                                int EU, int EI, int pbU, int NB, int* __restrict__ done){
    if (blockIdx.x == 0 && threadIdx.x == 0) *done = 0;   // reset completion counter each call
    if ((int)blockIdx.x < WSB){
        const int sid = blockIdx.x*256 + threadIdx.x;
        if (sid >= 3072) return;
        const float* W; int slot, base;
        if (sid < 1024)      { W = W1u; slot = sid;        base = 0;     }
        else if (sid < 2048) { W = W1i; slot = sid - 1024; base = 8192;  }
        else if (sid < 2560) { W = W2u; slot = sid - 2048; base = 16384; }
        else                 { W = W2i; slot = sid - 2560; base = 20480; }
        const int l  = slot & 63;
        const int ct = (slot >> 6) & 3;
        const int ks = slot >> 8;
        const int kb = ks*32 + (l >> 4)*8;
        const int c  = ct*16 + (l & 15);
        #pragma unroll
        for (int j = 0; j < 8; ++j){
            const float w = W[(size_t)(kb + j)*64 + c];
            const unsigned short h = f2bf(w);
            Bhi[(size_t)base + (size_t)slot*8 + j] = h;
            Blo[(size_t)base + (size_t)slot*8 + j] = f2bf(w - bf2f(h));
        }
        return;
    }
    extern __shared__ int sh[];                 // NB
    const int cb   = blockIdx.x - WSB;
    const int type = (cb >= pbU);
    const int blk  = type ? cb - pbU : cb;
    const int E    = type ? EI : EU;
    const int* dst = (type ? eiI : eiU) + E;
    int* chist     = (type ? chI : chU) + (size_t)blk * NB;
    for (int i = threadIdx.x; i < NB; i += 256) sh[i] = 0;
    __syncthreads();
    const int e0 = blk * PCHUNK;
    const int eend = min(e0 + PCHUNK, E);
    for (int e = e0 + threadIdx.x; e < eend; e += 256)
        atomicAdd(&sh[dst[e] >> 8], 1);
    __syncthreads();
    for (int i = threadIdx.x; i < NB; i += 256)
        chist[i] = sh[i];
}

// ---------------- link2: colscan + last-block bscan || gemm1 ----------------
__global__ __launch_bounds__(256) void hg_link2(int* __restrict__ chU, int* __restrict__ chI,
                                                int* __restrict__ bhU, int* __restrict__ bhI,
                                                int* __restrict__ boffU, int* __restrict__ boffI,
                                                int pbU, int pbI, int NB, int EU, int EI,
                                                int* __restrict__ done,
                                                const float* __restrict__ XU, const float* __restrict__ XI,
                                                const unsigned short* __restrict__ Bhi, const unsigned short* __restrict__ Blo,
                                                unsigned short* __restrict__ GU, unsigned short* __restrict__ GI,
                                                int NU, int NI, int gbU, int goff){
    GEMM_TAIL(2*NB)
    __shared__ int sc[256];
    __shared__ int winner;
    const int type = ((int)blockIdx.x >= NB);
    const int b    = type ? blockIdx.x - NB : blockIdx.x;
    int* chist     = type ? chI : chU;
    int* bh        = type ? bhI : bhU;
    const int nch  = type ? pbI : pbU;
    const int t = threadIdx.x;
    int carry = 0;
    for (int seg = 0; seg < nch; seg += 256){
        const int idx = seg + t;
        const int v = (idx < nch) ? chist[(size_t)idx*NB + b] : 0;
        sc[t] = v;
        __syncthreads();
        for (int off = 1; off < 256; off <<= 1){
            int x = 0;
            if (t >= off) x = sc[t-off];
            __syncthreads();
            if (t >= off) sc[t] += x;
            __syncthreads();
        }
        if (idx < nch) chist[(size_t)idx*NB + b] = carry + sc[t] - v;
        const int tot = sc[255];
        __syncthreads();
        carry += tot;
    }
    if (t == 0) bh[b] = carry;
    __threadfence();
    if (t == 0){
        const int old = atomicAdd(done, 1);
        winner = (old == 2*NB - 1);
    }
    __syncthreads();
    if (!winner) return;
    __threadfence();                            // acquire all bh writes
    for (int ty = 0; ty < 2; ++ty){
        const int* bhp = ty ? bhI : bhU;
        int* boff      = ty ? boffI : boffU;
        const int E    = ty ? EI : EU;
        const int i0 = 2*t, i1 = 2*t + 1;
        const int c0 = (i0 < NB) ? bhp[i0] : 0;
        const int c1 = (i1 < NB) ? bhp[i1] : 0;
        const int s = c0 + c1;
        sc[t] = s;
        __syncthreads();
        for (int off = 1; off < 256; off <<= 1){
            int x = 0;
            if (t >= off) x = sc[t-off];
            __syncthreads();
            if (t >= off) sc[t] += x;
            __syncthreads();
        }
        const int excl = sc[t] - s;
        if (i0 < NB) boff[i0] = excl;
        if (i1 < NB) boff[i1] = excl + c0;
        if (t == 0) boff[NB] = E;
        __syncthreads();
    }
}

// ---------------- link3: atomic-free partition || gemm1 ----------------
__global__ __launch_bounds__(256) void hg_link3(const int* __restrict__ eiU, const int* __restrict__ eiI,
                                                const int* __restrict__ chU, const int* __restrict__ chI,
                                                const int* __restrict__ boffU, const int* __restrict__ boffI,
                                                unsigned int* __restrict__ bkU, unsigned int* __restrict__ bkI,
                                                int EU, int EI, int pbU, int pbTot, int NB,
                                                const float* __restrict__ XU, const float* __restrict__ XI,
                                                const unsigned short* __restrict__ Bhi, const unsigned short* __restrict__ Blo,
                                                unsigned short* __restrict__ GU, unsigned short* __restrict__ GI,
                                                int NU, int NI, int gbU, int goff){
    GEMM_TAIL(pbTot)
    extern __shared__ int sh[];
    int* lofs  = sh;                 // NB
    int* lcur  = lofs + NB;          // NB
    int* lbase = lcur + NB;          // NB
    int* sc    = lbase + NB;         // 256
    unsigned int* stage = (unsigned int*)(sc + 256);   // PCHUNK
    int* gaddr = (int*)(stage + PCHUNK);               // PCHUNK

    const int type = ((int)blockIdx.x >= pbU);
    const int blk  = type ? blockIdx.x - pbU : blockIdx.x;
    const int E    = type ? EI : EU;
    const int* src = type ? eiI : eiU;
    const int* dst = src + E;
    const int* chist = (type ? chI : chU) + (size_t)blk * NB;
    const int* boff  = type ? boffI : boffU;
    unsigned int* bucketed = type ? bkI : bkU;

    const int t  = threadIdx.x;
    const int e0 = blk * PCHUNK;
    const int eend = min(e0 + PCHUNK, E);
    const int cnt  = eend - e0;

    int se[8], de[8];
    for (int i = t; i < NB; i += 256) lofs[i] = 0;
    __syncthreads();
    const int eb = e0 + t*8;
    if (eb + 8 <= E){
        const int4 sa = *(const int4*)(src + eb);
        const int4 sb = *(const int4*)(src + eb + 4);
        const int4 da = *(const int4*)(dst + eb);
        const int4 db = *(const int4*)(dst + eb + 4);
        se[0]=sa.x; se[1]=sa.y; se[2]=sa.z; se[3]=sa.w;
        se[4]=sb.x; se[5]=sb.y; se[6]=sb.z; se[7]=sb.w;
        de[0]=da.x; de[1]=da.y; de[2]=da.z; de[3]=da.w;
        de[4]=db.x; de[5]=db.y; de[6]=db.z; de[7]=db.w;
    } else {
        #pragma unroll
        for (int j = 0; j < 8; ++j){
            const int e = eb + j;
            se[j] = (e < E) ? src[e] : -1;
            de[j] = (e < E) ? dst[e] : -1;
        }
    }
    #pragma unroll
    for (int j = 0; j < 8; ++j)
        if (de[j] >= 0) atomicAdd(&lofs[de[j] >> 8], 1);
    __syncthreads();

    const int i0 = 2*t, i1 = 2*t + 1;
    const int c0 = (i0 < NB) ? lofs[i0] : 0;
    const int c1 = (i1 < NB) ? lofs[i1] : 0;
    if (i0 < NB) lbase[i0] = boff[i0] + chist[i0];
    if (i1 < NB) lbase[i1] = boff[i1] + chist[i1];
    const int s = c0 + c1;
    sc[t] = s;
    __syncthreads();
    for (int off = 1; off < 256; off <<= 1){
        int x = 0;
        if (t >= off) x = sc[t-off];
        __syncthreads();
        if (t >= off) sc[t] += x;
        __syncthreads();
    }
    const int excl = sc[t] - s;
    __syncthreads();
    if (i0 < NB){ lofs[i0] = excl;      lcur[i0] = excl; }
    if (i1 < NB){ lofs[i1] = excl + c0; lcur[i1] = excl + c0; }
    __syncthreads();

    #pragma unroll
    for (int j = 0; j < 8; ++j){
        if (de[j] >= 0){
            const int b = de[j] >> 8;
            const int p = atomicAdd(&lcur[b], 1);
            stage[p] = (unsigned int)se[j] | ((unsigned int)(de[j] & 255) << 24);
            gaddr[p] = lbase[b] + (p - lofs[b]);
        }
    }
    __syncthreads();

    for (int i = t; i < cnt; i += 256)
        bucketed[gaddr[i]] = stage[i];
}

// ---------------- link4: per-bucket deg/dinv/rowptr/counting-sort || gemm1 ----------------
__global__ __launch_bounds__(256) void hg_link4(const unsigned int* __restrict__ bkU, const unsigned int* __restrict__ bkI,
                                                const int* __restrict__ boffU, const int* __restrict__ boffI,
                                                float* __restrict__ dinvU, float* __restrict__ dinvI,
                                                int* __restrict__ rowptrU, int* __restrict__ rowptrI,
                                                int* __restrict__ csrU, int* __restrict__ csrI,
                                                int NU, int NI, int EU, int EI, int nbU, int nbTot,
                                                const float* __restrict__ XU, const float* __restrict__ XI,
                                                const unsigned short* __restrict__ Bhi, const unsigned short* __restrict__ Blo,
                                                unsigned short* __restrict__ GU, unsigned short* __restrict__ GI,
                                                int gbU, int goff){
    GEMM_TAIL(nbTot)
    __shared__ int hist[NPB];
    __shared__ int sc[NPB];
    __shared__ int cur[NPB];
    const int type = ((int)blockIdx.x >= nbU);
    const int b    = type ? blockIdx.x - nbU : blockIdx.x;
    const unsigned int* bucketed = type ? bkI : bkU;
    const int* boff = type ? boffI : boffU;
    float* dinv     = type ? dinvI : dinvU;
    int* rowptr     = type ? rowptrI : rowptrU;
    int* csr_src    = type ? csrI : csrU;
    const int N     = type ? NI : NU;
    const int E     = type ? EI : EU;

    const int t   = threadIdx.x;
    const int beg = boff[b], end = boff[b+1];
    hist[t] = 0;
    __syncthreads();
    for (int i = beg + t; i < end; i += 256)
        atomicAdd(&hist[bucketed[i] >> 24], 1);
    __syncthreads();
    const int d = hist[t];
    sc[t] = d;
    __syncthreads();
    for (int off = 1; off < 256; off <<= 1){
        int x = 0;
        if (t >= off) x = sc[t-off];
        __syncthreads();
        if (t >= off) sc[t] += x;
        __syncthreads();
    }
    const int excl = sc[t] - d;
    const int v = b*NPB + t;
    if (v < N){
        dinv[v]   = rsqrtf((float)(d + 1));     // +1 self-loop
        rowptr[v] = beg + excl;
    }
    if (b == 0 && t == 0) rowptr[N] = E;
    cur[t] = beg + excl;
    __syncthreads();
    for (int i = beg + t; i < end; i += 256){
        const unsigned int w = bucketed[i];
        const int p = atomicAdd(&cur[w >> 24], 1);
        csr_src[p] = (int)(w & 0x00FFFFFFu);
    }
}

// ---------------- gather core: acc[8] = self + sum_s g[s]*dinv[s] ----------------
__device__ __forceinline__ void gather_core(const unsigned short* __restrict__ g,
                                            const int* __restrict__ csr_src, const int* __restrict__ rowptr,
                                            const float* __restrict__ dinv, int v, int c8, bool ok,
                                            float* acc, float& dvv){
    int beg = 0, cnt = 0;
    dvv = 0.f;
    if (ok){ beg = rowptr[v]; cnt = rowptr[v+1] - beg; dvv = dinv[v]; }

    #pragma unroll
    for (int j = 0; j < 8; ++j) acc[j] = 0.f;
    if (ok){
        const u16x8 s = *(const u16x8*)(g + (size_t)v*64 + c8);
        #pragma unroll
        for (int j = 0; j < 8; ++j) acc[j] = bf2f(s[j]) * dvv;   // self-loop term
    }

    int i = 0;
    for (; i + 8 <= cnt; i += 8){
        const int s0 = csr_src[beg+i+0]; const int s1 = csr_src[beg+i+1];
        const int s2 = csr_src[beg+i+2]; const int s3 = csr_src[beg+i+3];
        const int s4 = csr_src[beg+i+4]; const int s5 = csr_src[beg+i+5];
        const int s6 = csr_src[beg+i+6]; const int s7 = csr_src[beg+i+7];
        const float dv0 = dinv[s0]; const float dv1 = dinv[s1];
        const float dv2 = dinv[s2]; const float dv3 = dinv[s3];
        const float dv4 = dinv[s4]; const float dv5 = dinv[s5];
        const float dv6 = dinv[s6]; const float dv7 = dinv[s7];
        const u16x8 x0 = *(const u16x8*)(g + (size_t)s0*64 + c8);
        const u16x8 x1 = *(const u16x8*)(g + (size_t)s1*64 + c8);
        const u16x8 x2 = *(const u16x8*)(g + (size_t)s2*64 + c8);
        const u16x8 x3 = *(const u16x8*)(g + (size_t)s3*64 + c8);
        const u16x8 x4 = *(const u16x8*)(g + (size_t)s4*64 + c8);
        const u16x8 x5 = *(const u16x8*)(g + (size_t)s5*64 + c8);
        const u16x8 x6 = *(const u16x8*)(g + (size_t)s6*64 + c8);
        const u16x8 x7 = *(const u16x8*)(g + (size_t)s7*64 + c8);
        #pragma unroll
        for (int j = 0; j < 8; ++j){
            float a = fmaf(bf2f(x0[j]), dv0, fmaf(bf2f(x1[j]), dv1, fmaf(bf2f(x2[j]), dv2, bf2f(x3[j]) * dv3)));
            float c = fmaf(bf2f(x4[j]), dv4, fmaf(bf2f(x5[j]), dv5, fmaf(bf2f(x6[j]), dv6, bf2f(x7[j]) * dv7)));
            acc[j] += a + c;
        }
    }
    for (; i + 4 <= cnt; i += 4){
        const int s0 = csr_src[beg+i+0]; const int s1 = csr_src[beg+i+1];
        const int s2 = csr_src[beg+i+2]; const int s3 = csr_src[beg+i+3];
        const float dv0 = dinv[s0]; const float dv1 = dinv[s1];
        const float dv2 = dinv[s2]; const float dv3 = dinv[s3];
        const u16x8 x0 = *(const u16x8*)(g + (size_t)s0*64 + c8);
        const u16x8 x1 = *(const u16x8*)(g + (size_t)s1*64 + c8);
        const u16x8 x2 = *(const u16x8*)(g + (size_t)s2*64 + c8);
        const u16x8 x3 = *(const u16x8*)(g + (size_t)s3*64 + c8);
        #pragma unroll
        for (int j = 0; j < 8; ++j)
            acc[j] += fmaf(bf2f(x0[j]), dv0, fmaf(bf2f(x1[j]), dv1, fmaf(bf2f(x2[j]), dv2, bf2f(x3[j]) * dv3)));
    }
    for (; i < cnt; ++i){
        const int s0 = csr_src[beg+i];
        const float dv0 = dinv[s0];
        const u16x8 x0 = *(const u16x8*)(g + (size_t)s0*64 + c8);
        #pragma unroll
        for (int j = 0; j < 8; ++j) acc[j] = fmaf(bf2f(x0[j]), dv0, acc[j]);
    }
}

// ---------------- fused: aggregate layer 1 + gemm layer 2 (MFMA) -> G2 bf16 ----------------
__global__ __launch_bounds__(256) void hg_agg_gemm2(const unsigned short* __restrict__ gU, const unsigned short* __restrict__ gI,
                                                    const int* __restrict__ csrU, const int* __restrict__ csrI,
                                                    const int* __restrict__ rowptrU, const int* __restrict__ rowptrI,
                                                    const float* __restrict__ dinvU, const float* __restrict__ dinvI,
                                                    const float* __restrict__ bU, const float* __restrict__ bI,
                                                    const unsigned short* __restrict__ Bhi, const unsigned short* __restrict__ Blo,
                                                    unsigned short* __restrict__ G2U, unsigned short* __restrict__ G2I,
                                                    int NU, int NI, int nbU){
    __shared__ float hrow[32*68];
    const int type = ((int)blockIdx.x >= nbU);
    const int blk  = type ? blockIdx.x - nbU : blockIdx.x;
    const unsigned short* g = type ? gI : gU;
    const int* csr_src = type ? csrI : csrU;
    const int* rowptr  = type ? rowptrI : rowptrU;
    const float* dinv  = type ? dinvI : dinvU;
    const float* b     = type ? bI : bU;
    unsigned short* G2 = type ? G2I : G2U;
    const int N        = type ? NI : NU;
    const unsigned short* Bh = Bhi + (type ? 20480 : 16384);
    const unsigned short* Bl = Blo + (type ? 20480 : 16384);

    const int t = threadIdx.x;
    const int nodeLocal = t >> 3;
    const int c8 = (t & 7) << 3;
    const int v = blk*32 + nodeLocal;
    const bool ok = (v < N);

    float acc[8]; float dvv;
    gather_core(g, csr_src, rowptr, dinv, v, c8, ok, acc, dvv);

    {
        const float4 b0 = *(const float4*)(b + c8);
        const float4 b1 = *(const float4*)(b + c8 + 4);
        float r0 = ok ? fmaxf(fmaf(acc[0], dvv, b0.x), 0.f) : 0.f;
        float r1 = ok ? fmaxf(fmaf(acc[1], dvv, b0.y), 0.f) : 0.f;
        float r2 = ok ? fmaxf(fmaf(acc[2], dvv, b0.z), 0.f) : 0.f;
        float r3 = ok ? fmaxf(fmaf(acc[3], dvv, b0.w), 0.f) : 0.f;
        float r4 = ok ? fmaxf(fmaf(acc[4], dvv, b1.x), 0.f) : 0.f;
        float r5 = ok ? fmaxf(fmaf(acc[5], dvv, b1.y), 0.f) : 0.f;
        float r6 = ok ? fmaxf(fmaf(acc[6], dvv, b1.z), 0.f) : 0.f;
        float r7 = ok ? fmaxf(fmaf(acc[7], dvv, b1.w), 0.f) : 0.f;
        float* hr = hrow + nodeLocal*68 + c8;
        hr[0]=r0; hr[1]=r1; hr[2]=r2; hr[3]=r3; hr[4]=r4; hr[5]=r5; hr[6]=r6; hr[7]=r7;
    }
    __syncthreads();

    const int l  = t & 63;
    const int wv = t >> 6;
    const int rbase  = (wv & 1) * 16;
    const int ctbase = (wv >> 1) * 2;

    f32x4 acc2[2];
    acc2[0] = (f32x4){0.f,0.f,0.f,0.f};
    acc2[1] = (f32x4){0.f,0.f,0.f,0.f};

    const int arow = rbase + (l & 15);
    const int kg   = (l >> 4) * 8;
    #pragma unroll
    for (int ks = 0; ks < 2; ++ks){
        const float* hr = hrow + arow*68 + ks*32 + kg;
        const float4 a = *(const float4*)(hr);
        const float4 c = *(const float4*)(hr + 4);
        float xv[8] = {a.x,a.y,a.z,a.w,c.x,c.y,c.z,c.w};
        bf16x8 ahi, alo;
        #pragma unroll
        for (int j = 0; j < 8; ++j){
            const unsigned short h = f2bf(xv[j]);
            ahi[j] = (short)h;
            alo[j] = (short)f2bf(xv[j] - bf2f(h));
        }
        #pragma unroll
        for (int ct = 0; ct < 2; ++ct){
            const int slot = (ks*4 + ctbase + ct)*64 + l;
            const bf16x8 bhi = *(const bf16x8*)(Bh + (size_t)slot*8);
            const bf16x8 blo = *(const bf16x8*)(Bl + (size_t)slot*8);
            acc2[ct] = __builtin_amdgcn_mfma_f32_16x16x32_bf16(ahi, bhi, acc2[ct], 0, 0, 0);
            acc2[ct] = __builtin_amdgcn_mfma_f32_16x16x32_bf16(alo, bhi, acc2[ct], 0, 0, 0);
            acc2[ct] = __builtin_amdgcn_mfma_f32_16x16x32_bf16(ahi, blo, acc2[ct], 0, 0, 0);
        }
    }

    const int orow0 = rbase + (l >> 4)*4;
    const int ocol  = l & 15;
    #pragma unroll
    for (int r = 0; r < 4; ++r){
        const int gv = blk*32 + orow0 + r;
        if (gv < N){
            #pragma unroll
            for (int ct = 0; ct < 2; ++ct)
                G2[(size_t)gv*64 + (ctbase + ct)*16 + ocol] = f2bf(acc2[ct][r]);
        }
    }
}

// ---------------- aggregate layer 2 + fused head ----------------
__global__ __launch_bounds__(256) void hg_agghead(const unsigned short* __restrict__ gU, const unsigned short* __restrict__ gI,
                                                  const int* __restrict__ csrU, const int* __restrict__ csrI,
                                                  const int* __restrict__ rowptrU, const int* __restrict__ rowptrI,
                                                  const float* __restrict__ dinvU, const float* __restrict__ dinvI,
                                                  const float* __restrict__ bU, const float* __restrict__ bI,
                                                  const float* __restrict__ WlU, const float* __restrict__ WlI,
                                                  const float* __restrict__ blU, const float* __restrict__ blI,
                                                  float* __restrict__ outU, float* __restrict__ outI,
                                                  int NU, int NI, int nbU){
    const int type = ((int)blockIdx.x >= nbU);
    const int blk  = type ? blockIdx.x - nbU : blockIdx.x;
    const unsigned short* g = type ? gI : gU;
    const int* csr_src = type ? csrI : csrU;
    const int* rowptr  = type ? rowptrI : rowptrU;
    const float* dinv  = type ? dinvI : dinvU;
    const float* b     = type ? bI : bU;
    const float* Wl    = type ? WlI : WlU;
    const float* bl    = type ? blI : blU;
    float* outp        = type ? outI : outU;
    const int N        = type ? NI : NU;

    const int t = threadIdx.x;
    const int nodeLocal = t >> 3;
    const int c8 = (t & 7) << 3;
    const int v = blk*32 + nodeLocal;
    const bool ok = (v < N);

    float acc[8]; float dvv;
    gather_core(g, csr_src, rowptr, dinv, v, c8, ok, acc, dvv);

    float r[8];
    {
        const float4 b0 = *(const float4*)(b + c8);
        const float4 b1 = *(const float4*)(b + c8 + 4);
        r[0] = fmaxf(fmaf(acc[0], dvv, b0.x), 0.f);
        r[1] = fmaxf(fmaf(acc[1], dvv, b0.y), 0.f);
        r[2] = fmaxf(fmaf(acc[2], dvv, b0.z), 0.f);
        r[3] = fmaxf(fmaf(acc[3], dvv, b0.w), 0.f);
        r[4] = fmaxf(fmaf(acc[4], dvv, b1.x), 0.f);
        r[5] = fmaxf(fmaf(acc[5], dvv, b1.y), 0.f);
        r[6] = fmaxf(fmaf(acc[6], dvv, b1.z), 0.f);
        r[7] = fmaxf(fmaf(acc[7], dvv, b1.w), 0.f);
    }

    float p0 = 0.f, p1 = 0.f;
    #pragma unroll
    for (int j = 0; j < 8; ++j){
        const float2 wl = *(const float2*)(Wl + (size_t)(c8 + j)*2);
        p0 = fmaf(r[j], wl.x, p0);
        p1 = fmaf(r[j], wl.y, p1);
    }
    p0 += __shfl_xor(p0, 1); p1 += __shfl_xor(p1, 1);
    p0 += __shfl_xor(p0, 2); p1 += __shfl_xor(p1, 2);
    p0 += __shfl_xor(p0, 4); p1 += __shfl_xor(p1, 4);
    if (ok && (t & 7) == 0){
        float2 o; o.x = p0 + bl[0]; o.y = p1 + bl[1];
        *(float2*)(outp + (size_t)v*2) = o;
    }
}

extern "C" void kernel_launch(void* const* d_in, const int* in_sizes, int n_in,
                              void* d_out, int out_size, void* d_ws, size_t ws_size,
                              hipStream_t stream) {
    const float* x_user = (const float*)d_in[0];
    const float* x_item = (const float*)d_in[1];
    const int*  ei_user = (const int*)d_in[2];
    const int*  ei_item = (const int*)d_in[3];
    const float* W1_user = (const float*)d_in[4];
    const float* b1_user = (const float*)d_in[5];
    const float* W1_item = (const float*)d_in[6];
    const float* b1_item = (const float*)d_in[7];
    const float* W2_user = (const float*)d_in[8];
    const float* b2_user = (const float*)d_in[9];
    const float* W2_item = (const float*)d_in[10];
    const float* b2_item = (const float*)d_in[11];
    const float* Wl_user = (const float*)d_in[12];
    const float* bl_user = (const float*)d_in[13];
    const float* Wl_item = (const float*)d_in[14];
    const float* bl_item = (const float*)d_in[15];

    const int NU = in_sizes[0] / 128;
    const int NI = in_sizes[1] / 128;
    const int EU = in_sizes[2] / 2;
    const int EI = in_sizes[3] / 2;
    const int NBU = CDIV(NU, NPB);
    const int NBI = CDIV(NI, NPB);
    const int NB  = (NBU > NBI) ? NBU : NBI;
    const int pbU = CDIV(EU, PCHUNK), pbI = CDIV(EI, PCHUNK);

    char* w = (char*)d_ws;
    unsigned short* GU = (unsigned short*)w;    w += (size_t)NU * 64 * sizeof(unsigned short);
    unsigned short* GI = (unsigned short*)w;    w += (size_t)NI * 64 * sizeof(unsigned short);
    unsigned short* G2U = (unsigned short*)w;   w += (size_t)NU * 64 * sizeof(unsigned short);
    unsigned short* G2I = (unsigned short*)w;   w += (size_t)NI * 64 * sizeof(unsigned short);
    float* dinvU = (float*)w;                   w += (size_t)NU * sizeof(float);
    float* dinvI = (float*)w;                   w += (size_t)NI * sizeof(float);
    int* rowptrU = (int*)w;                     w += ((size_t)NU + 1) * sizeof(int);
    int* rowptrI = (int*)w;                     w += ((size_t)NI + 1) * sizeof(int);
    int* csrU = (int*)w;                        w += (size_t)EU * sizeof(int);
    int* csrI = (int*)w;                        w += (size_t)EI * sizeof(int);
    unsigned int* bkU = (unsigned int*)w;       w += (size_t)EU * sizeof(int);
    unsigned int* bkI = (unsigned int*)w;       w += (size_t)EI * sizeof(int);
    int* chU = (int*)w;                         w += (size_t)pbU * NB * sizeof(int);
    int* chI = (int*)w;                         w += (size_t)pbI * NB * sizeof(int);
    int* bhU = (int*)w;                         w += (size_t)NB * sizeof(int);
    int* bhI = (int*)w;                         w += (size_t)NB * sizeof(int);
    int* boffU = (int*)w;                       w += ((size_t)NB + 1) * sizeof(int);
    int* boffI = (int*)w;                       w += ((size_t)NB + 1) * sizeof(int);
    int* done  = (int*)w;                       w += sizeof(int);
    unsigned short* Bhi = (unsigned short*)w;   w += (size_t)24576 * sizeof(unsigned short);
    unsigned short* Blo = (unsigned short*)w;   w += (size_t)24576 * sizeof(unsigned short);

    float* out  = (float*)d_out;
    float* outU = out;
    float* outI = out + (size_t)2 * NU;

    // gemm1 shares across links 2-4
    const int gbU = CDIV(NU, 64), gbI = CDIV(NI, 64);
    const int GB = gbU + gbI;
    const int q = GB / 3;
    const int c2 = q, c3 = q, c4 = GB - 2*q;

    // link1: wsplit + chist (+ done reset)
    hg_link1<<<WSB + pbU + pbI, 256, NB*sizeof(int), stream>>>(
        W1_user, W1_item, W2_user, W2_item, Bhi, Blo,
        ei_user, ei_item, chU, chI, EU, EI, pbU, NB, done);

    // link2: colscan + last-block bscan || gemm1 slice A
    hg_link2<<<2*NB + c2, 256, 0, stream>>>(
        chU, chI, bhU, bhI, boffU, boffI, pbU, pbI, NB, EU, EI, done,
        x_user, x_item, Bhi, Blo, GU, GI, NU, NI, gbU, 0);

    // link3: partition || gemm1 slice B
    const size_t p5lds = (size_t)(3*NB + 256 + 2*PCHUNK) * sizeof(int);
    hg_link3<<<pbU + pbI + c3, 256, p5lds, stream>>>(
        ei_user, ei_item, chU, chI, boffU, boffI, bkU, bkI, EU, EI, pbU, pbU + pbI, NB,
        x_user, x_item, Bhi, Blo, GU, GI, NU, NI, gbU, c2);

    // link4: bucket build || gemm1 slice C
    hg_link4<<<NBU + NBI + c4, 256, 0, stream>>>(
        bkU, bkI, boffU, boffI, dinvU, dinvI, rowptrU, rowptrI, csrU, csrI,
        NU, NI, EU, EI, NBU, NBU + NBI,
        x_user, x_item, Bhi, Blo, GU, GI, gbU, c2 + c3);

    // aggregate layer 1 + gemm layer 2 fused -> G2
    const int abU = CDIV(NU, 32), abI = CDIV(NI, 32);
    hg_agg_gemm2<<<abU + abI, 256, 0, stream>>>(GU, GI, csrU, csrI, rowptrU, rowptrI,
                                                dinvU, dinvI, b1_user, b1_item,
                                                Bhi, Blo, G2U, G2I, NU, NI, abU);

    // aggregate layer 2 + fused head
    hg_agghead<<<abU + abI, 256, 0, stream>>>(G2U, G2I, csrU, csrI, rowptrU, rowptrI,
                                              dinvU, dinvI, b2_user, b2_item,
                                              Wl_user, Wl_item, bl_user, bl_item,
                                              outU, outI, NU, NI, abU);
}

// Round 18
// 232.397 us; speedup vs baseline: 1.3466x; 1.3466x over previous
//
#include <hip/hip_runtime.h>

#define CDIV(a,b) (((a)+(b)-1)/(b))
#define NPB 256     // nodes per bucket; bucket(d) = d >> 8
#define PCHUNK 2048 // edges per partition chunk
#define WSB 12      // wsplit blocks

typedef __attribute__((ext_vector_type(8))) short bf16x8;
typedef __attribute__((ext_vector_type(8))) unsigned short u16x8;
typedef __attribute__((ext_vector_type(4))) float f32x4;

__device__ __forceinline__ unsigned short f2bf(float x){
    unsigned int u = __float_as_uint(x);
    unsigned int r = u + 0x7FFFu + ((u >> 16) & 1u);   // RNE
    return (unsigned short)(r >> 16);
}
__device__ __forceinline__ float bf2f(unsigned short h){
    return __uint_as_float(((unsigned int)h) << 16);
}

// ---------------- gemm layer-1 body (K=128, no dinv) ----------------
__device__ __forceinline__ void gemm1_body(int gb,
                                           const float* __restrict__ XU, const float* __restrict__ XI,
                                           const unsigned short* __restrict__ Bhi, const unsigned short* __restrict__ Blo,
                                           unsigned short* __restrict__ GU, unsigned short* __restrict__ GI,
                                           int NU, int NI, int gbU){
    const int type = (gb >= gbU);
    const int blk  = type ? gb - gbU : gb;
    const float* X = type ? XI : XU;
    unsigned short* G = type ? GI : GU;
    const int N    = type ? NI : NU;
    const unsigned short* Bh = Bhi + (type ? 8192 : 0);
    const unsigned short* Bl = Blo + (type ? 8192 : 0);

    const int l = threadIdx.x & 63;
    const int w = threadIdx.x >> 6;
    const int row0 = blk*64 + w*16;
    if (row0 >= N) return;

    f32x4 acc[4];
    #pragma unroll
    for (int ct = 0; ct < 4; ++ct) acc[ct] = (f32x4){0.f,0.f,0.f,0.f};

    const int rA = row0 + (l & 15);
    const int kg = (l >> 4) * 8;
    const bool rowok = (rA < N);
    const float* xrow = X + (size_t)rA * 128;

    #pragma unroll
    for (int ks = 0; ks < 4; ++ks){
        float xv[8];
        if (rowok){
            const float4 a = *(const float4*)(xrow + ks*32 + kg);
            const float4 b = *(const float4*)(xrow + ks*32 + kg + 4);
            xv[0]=a.x; xv[1]=a.y; xv[2]=a.z; xv[3]=a.w;
            xv[4]=b.x; xv[5]=b.y; xv[6]=b.z; xv[7]=b.w;
        } else {
            #pragma unroll
            for (int j = 0; j < 8; ++j) xv[j] = 0.f;
        }
        bf16x8 ahi, alo;
        #pragma unroll
        for (int j = 0; j < 8; ++j){
            const unsigned short h = f2bf(xv[j]);
            ahi[j] = (short)h;
            alo[j] = (short)f2bf(xv[j] - bf2f(h));
        }
        #pragma unroll
        for (int ct = 0; ct < 4; ++ct){
            const bf16x8 bhi = *(const bf16x8*)(Bh + ((size_t)(ks*4 + ct)*64 + l)*8);
            const bf16x8 blo = *(const bf16x8*)(Bl + ((size_t)(ks*4 + ct)*64 + l)*8);
            acc[ct] = __builtin_amdgcn_mfma_f32_16x16x32_bf16(ahi, bhi, acc[ct], 0, 0, 0);
            acc[ct] = __builtin_amdgcn_mfma_f32_16x16x32_bf16(alo, bhi, acc[ct], 0, 0, 0);
            acc[ct] = __builtin_amdgcn_mfma_f32_16x16x32_bf16(ahi, blo, acc[ct], 0, 0, 0);
        }
    }

    const int orow0 = row0 + (l >> 4)*4;
    const int ocol  = l & 15;
    #pragma unroll
    for (int r = 0; r < 4; ++r){
        const int orow = orow0 + r;
        if (orow < N){
            #pragma unroll
            for (int ct = 0; ct < 4; ++ct)
                G[(size_t)orow*64 + ct*16 + ocol] = f2bf(acc[ct][r]);
        }
    }
}

#define GEMM_TAIL(taskTot) \
    if ((int)blockIdx.x >= (taskTot)){ \
        gemm1_body(goff + blockIdx.x - (taskTot), XU, XI, Bhi, Blo, GU, GI, NU, NI, gbU); \
        return; \
    }

// ---------------- link1: wsplit (blocks 0..WSB) + chist ----------------
__global__ __launch_bounds__(256) void hg_link1(const float* __restrict__ W1u, const float* __restrict__ W1i,
                                                const float* __restrict__ W2u, const float* __restrict__ W2i,
                                                unsigned short* __restrict__ Bhi, unsigned short* __restrict__ Blo,
                                                const int* __restrict__ eiU, const int* __restrict__ eiI,
                                                int* __restrict__ chU, int* __restrict__ chI,
                                                int EU, int EI, int pbU, int NB){
    if ((int)blockIdx.x < WSB){
        const int sid = blockIdx.x*256 + threadIdx.x;
        if (sid >= 3072) return;
        const float* W; int slot, base;
        if (sid < 1024)      { W = W1u; slot = sid;        base = 0;     }
        else if (sid < 2048) { W = W1i; slot = sid - 1024; base = 8192;  }
        else if (sid < 2560) { W = W2u; slot = sid - 2048; base = 16384; }
        else                 { W = W2i; slot = sid - 2560; base = 20480; }
        const int l  = slot & 63;
        const int ct = (slot >> 6) & 3;
        const int ks = slot >> 8;
        const int kb = ks*32 + (l >> 4)*8;
        const int c  = ct*16 + (l & 15);
        #pragma unroll
        for (int j = 0; j < 8; ++j){
            const float w = W[(size_t)(kb + j)*64 + c];
            const unsigned short h = f2bf(w);
            Bhi[(size_t)base + (size_t)slot*8 + j] = h;
            Blo[(size_t)base + (size_t)slot*8 + j] = f2bf(w - bf2f(h));
        }
        return;
    }
    extern __shared__ int sh[];                 // NB
    const int cb   = blockIdx.x - WSB;
    const int type = (cb >= pbU);
    const int blk  = type ? cb - pbU : cb;
    const int E    = type ? EI : EU;
    const int* dst = (type ? eiI : eiU) + E;
    int* chist     = (type ? chI : chU) + (size_t)blk * NB;
    for (int i = threadIdx.x; i < NB; i += 256) sh[i] = 0;
    __syncthreads();
    const int e0 = blk * PCHUNK;
    const int eend = min(e0 + PCHUNK, E);
    for (int e = e0 + threadIdx.x; e < eend; e += 256)
        atomicAdd(&sh[dst[e] >> 8], 1);
    __syncthreads();
    for (int i = threadIdx.x; i < NB; i += 256)
        chist[i] = sh[i];
}

// ---------------- link2: colscan || gemm1 ----------------
__global__ __launch_bounds__(256) void hg_link2(int* __restrict__ chU, int* __restrict__ chI,
                                                int* __restrict__ bhU, int* __restrict__ bhI,
                                                int pbU, int pbI, int NB,
                                                const float* __restrict__ XU, const float* __restrict__ XI,
                                                const unsigned short* __restrict__ Bhi, const unsigned short* __restrict__ Blo,
                                                unsigned short* __restrict__ GU, unsigned short* __restrict__ GI,
                                                int NU, int NI, int gbU, int goff){
    GEMM_TAIL(2*NB)
    __shared__ int sc[256];
    const int type = ((int)blockIdx.x >= NB);
    const int b    = type ? blockIdx.x - NB : blockIdx.x;
    int* chist     = type ? chI : chU;
    int* bh        = type ? bhI : bhU;
    const int nch  = type ? pbI : pbU;
    const int t = threadIdx.x;
    int carry = 0;
    for (int seg = 0; seg < nch; seg += 256){
        const int idx = seg + t;
        const int v = (idx < nch) ? chist[(size_t)idx*NB + b] : 0;
        sc[t] = v;
        __syncthreads();
        for (int off = 1; off < 256; off <<= 1){
            int x = 0;
            if (t >= off) x = sc[t-off];
            __syncthreads();
            if (t >= off) sc[t] += x;
            __syncthreads();
        }
        if (idx < nch) chist[(size_t)idx*NB + b] = carry + sc[t] - v;
        const int tot = sc[255];
        __syncthreads();
        carry += tot;
    }
    if (t == 0) bh[b] = carry;
}

// ---------------- link3: bscan || gemm1 ----------------
__global__ __launch_bounds__(256) void hg_link3(const int* __restrict__ bhU, const int* __restrict__ bhI,
                                                int* __restrict__ boffU, int* __restrict__ boffI,
                                                int NB, int EU, int EI,
                                                const float* __restrict__ XU, const float* __restrict__ XI,
                                                const unsigned short* __restrict__ Bhi, const unsigned short* __restrict__ Blo,
                                                unsigned short* __restrict__ GU, unsigned short* __restrict__ GI,
                                                int NU, int NI, int gbU, int goff){
    GEMM_TAIL(2)
    __shared__ int sc[256];
    const int type = blockIdx.x;
    const int* bh = type ? bhI : bhU;
    int* boff     = type ? boffI : boffU;
    const int E   = type ? EI : EU;
    const int t = threadIdx.x;
    const int i0 = 2*t, i1 = 2*t + 1;
    const int c0 = (i0 < NB) ? bh[i0] : 0;
    const int c1 = (i1 < NB) ? bh[i1] : 0;
    const int s = c0 + c1;
    sc[t] = s;
    __syncthreads();
    for (int off = 1; off < 256; off <<= 1){
        int x = 0;
        if (t >= off) x = sc[t-off];
        __syncthreads();
        if (t >= off) sc[t] += x;
        __syncthreads();
    }
    const int excl = sc[t] - s;
    if (i0 < NB) boff[i0] = excl;
    if (i1 < NB) boff[i1] = excl + c0;
    if (t == 0) boff[NB] = E;
}

// ---------------- link4: atomic-free partition || gemm1 ----------------
__global__ __launch_bounds__(256) void hg_link4(const int* __restrict__ eiU, const int* __restrict__ eiI,
                                                const int* __restrict__ chU, const int* __restrict__ chI,
                                                const int* __restrict__ boffU, const int* __restrict__ boffI,
                                                unsigned int* __restrict__ bkU, unsigned int* __restrict__ bkI,
                                                int EU, int EI, int pbU, int pbTot, int NB,
                                                const float* __restrict__ XU, const float* __restrict__ XI,
                                                const unsigned short* __restrict__ Bhi, const unsigned short* __restrict__ Blo,
                                                unsigned short* __restrict__ GU, unsigned short* __restrict__ GI,
                                                int NU, int NI, int gbU, int goff){
    GEMM_TAIL(pbTot)
    extern __shared__ int sh[];
    int* lofs  = sh;                 // NB
    int* lcur  = lofs + NB;          // NB
    int* lbase = lcur + NB;          // NB
    int* sc    = lbase + NB;         // 256
    unsigned int* stage = (unsigned int*)(sc + 256);   // PCHUNK
    int* gaddr = (int*)(stage + PCHUNK);               // PCHUNK

    const int type = ((int)blockIdx.x >= pbU);
    const int blk  = type ? blockIdx.x - pbU : blockIdx.x;
    const int E    = type ? EI : EU;
    const int* src = type ? eiI : eiU;
    const int* dst = src + E;
    const int* chist = (type ? chI : chU) + (size_t)blk * NB;
    const int* boff  = type ? boffI : boffU;
    unsigned int* bucketed = type ? bkI : bkU;

    const int t  = threadIdx.x;
    const int e0 = blk * PCHUNK;
    const int eend = min(e0 + PCHUNK, E);
    const int cnt  = eend - e0;

    int se[8], de[8];
    for (int i = t; i < NB; i += 256) lofs[i] = 0;
    __syncthreads();
    const int eb = e0 + t*8;
    if (eb + 8 <= E){
        const int4 sa = *(const int4*)(src + eb);
        const int4 sb = *(const int4*)(src + eb + 4);
        const int4 da = *(const int4*)(dst + eb);
        const int4 db = *(const int4*)(dst + eb + 4);
        se[0]=sa.x; se[1]=sa.y; se[2]=sa.z; se[3]=sa.w;
        se[4]=sb.x; se[5]=sb.y; se[6]=sb.z; se[7]=sb.w;
        de[0]=da.x; de[1]=da.y; de[2]=da.z; de[3]=da.w;
        de[4]=db.x; de[5]=db.y; de[6]=db.z; de[7]=db.w;
    } else {
        #pragma unroll
        for (int j = 0; j < 8; ++j){
            const int e = eb + j;
            se[j] = (e < E) ? src[e] : -1;
            de[j] = (e < E) ? dst[e] : -1;
        }
    }
    #pragma unroll
    for (int j = 0; j < 8; ++j)
        if (de[j] >= 0) atomicAdd(&lofs[de[j] >> 8], 1);
    __syncthreads();

    const int i0 = 2*t, i1 = 2*t + 1;
    const int c0 = (i0 < NB) ? lofs[i0] : 0;
    const int c1 = (i1 < NB) ? lofs[i1] : 0;
    if (i0 < NB) lbase[i0] = boff[i0] + chist[i0];
    if (i1 < NB) lbase[i1] = boff[i1] + chist[i1];
    const int s = c0 + c1;
    sc[t] = s;
    __syncthreads();
    for (int off = 1; off < 256; off <<= 1){
        int x = 0;
        if (t >= off) x = sc[t-off];
        __syncthreads();
        if (t >= off) sc[t] += x;
        __syncthreads();
    }
    const int excl = sc[t] - s;
    __syncthreads();
    if (i0 < NB){ lofs[i0] = excl;      lcur[i0] = excl; }
    if (i1 < NB){ lofs[i1] = excl + c0; lcur[i1] = excl + c0; }
    __syncthreads();

    #pragma unroll
    for (int j = 0; j < 8; ++j){
        if (de[j] >= 0){
            const int b = de[j] >> 8;
            const int p = atomicAdd(&lcur[b], 1);
            stage[p] = (unsigned int)se[j] | ((unsigned int)(de[j] & 255) << 24);
            gaddr[p] = lbase[b] + (p - lofs[b]);
        }
    }
    __syncthreads();

    for (int i = t; i < cnt; i += 256)
        bucketed[gaddr[i]] = stage[i];
}

// ---------------- link5: per-bucket deg/dinv/rowptr/counting-sort || gemm1 ----------------
__global__ __launch_bounds__(256) void hg_link5(const unsigned int* __restrict__ bkU, const unsigned int* __restrict__ bkI,
                                                const int* __restrict__ boffU, const int* __restrict__ boffI,
                                                float* __restrict__ dinvU, float* __restrict__ dinvI,
                                                int* __restrict__ rowptrU, int* __restrict__ rowptrI,
                                                int* __restrict__ csrU, int* __restrict__ csrI,
                                                int NU, int NI, int EU, int EI, int nbU, int nbTot,
                                                const float* __restrict__ XU, const float* __restrict__ XI,
                                                const unsigned short* __restrict__ Bhi, const unsigned short* __restrict__ Blo,
                                                unsigned short* __restrict__ GU, unsigned short* __restrict__ GI,
                                                int gbU, int goff){
    GEMM_TAIL(nbTot)
    __shared__ int hist[NPB];
    __shared__ int sc[NPB];
    __shared__ int cur[NPB];
    const int type = ((int)blockIdx.x >= nbU);
    const int b    = type ? blockIdx.x - nbU : blockIdx.x;
    const unsigned int* bucketed = type ? bkI : bkU;
    const int* boff = type ? boffI : boffU;
    float* dinv     = type ? dinvI : dinvU;
    int* rowptr     = type ? rowptrI : rowptrU;
    int* csr_src    = type ? csrI : csrU;
    const int N     = type ? NI : NU;
    const int E     = type ? EI : EU;

    const int t   = threadIdx.x;
    const int beg = boff[b], end = boff[b+1];
    hist[t] = 0;
    __syncthreads();
    for (int i = beg + t; i < end; i += 256)
        atomicAdd(&hist[bucketed[i] >> 24], 1);
    __syncthreads();
    const int d = hist[t];
    sc[t] = d;
    __syncthreads();
    for (int off = 1; off < 256; off <<= 1){
        int x = 0;
        if (t >= off) x = sc[t-off];
        __syncthreads();
        if (t >= off) sc[t] += x;
        __syncthreads();
    }
    const int excl = sc[t] - d;
    const int v = b*NPB + t;
    if (v < N){
        dinv[v]   = rsqrtf((float)(d + 1));     // +1 self-loop
        rowptr[v] = beg + excl;
    }
    if (b == 0 && t == 0) rowptr[N] = E;
    cur[t] = beg + excl;
    __syncthreads();
    for (int i = beg + t; i < end; i += 256){
        const unsigned int w = bucketed[i];
        const int p = atomicAdd(&cur[w >> 24], 1);
        csr_src[p] = (int)(w & 0x00FFFFFFu);
    }
}

// ---------------- gather core: acc[8] = self + sum_s g[s]*dinv[s] ----------------
__device__ __forceinline__ void gather_core(const unsigned short* __restrict__ g,
                                            const int* __restrict__ csr_src, const int* __restrict__ rowptr,
                                            const float* __restrict__ dinv, int v, int c8, bool ok,
                                            float* acc, float& dvv){
    int beg = 0, cnt = 0;
    dvv = 0.f;
    if (ok){ beg = rowptr[v]; cnt = rowptr[v+1] - beg; dvv = dinv[v]; }

    #pragma unroll
    for (int j = 0; j < 8; ++j) acc[j] = 0.f;
    if (ok){
        const u16x8 s = *(const u16x8*)(g + (size_t)v*64 + c8);
        #pragma unroll
        for (int j = 0; j < 8; ++j) acc[j] = bf2f(s[j]) * dvv;   // self-loop term
    }

    int i = 0;
    for (; i + 8 <= cnt; i += 8){
        const int s0 = csr_src[beg+i+0]; const int s1 = csr_src[beg+i+1];
        const int s2 = csr_src[beg+i+2]; const int s3 = csr_src[beg+i+3];
        const int s4 = csr_src[beg+i+4]; const int s5 = csr_src[beg+i+5];
        const int s6 = csr_src[beg+i+6]; const int s7 = csr_src[beg+i+7];
        const float dv0 = dinv[s0]; const float dv1 = dinv[s1];
        const float dv2 = dinv[s2]; const float dv3 = dinv[s3];
        const float dv4 = dinv[s4]; const float dv5 = dinv[s5];
        const float dv6 = dinv[s6]; const float dv7 = dinv[s7];
        const u16x8 x0 = *(const u16x8*)(g + (size_t)s0*64 + c8);
        const u16x8 x1 = *(const u16x8*)(g + (size_t)s1*64 + c8);
        const u16x8 x2 = *(const u16x8*)(g + (size_t)s2*64 + c8);
        const u16x8 x3 = *(const u16x8*)(g + (size_t)s3*64 + c8);
        const u16x8 x4 = *(const u16x8*)(g + (size_t)s4*64 + c8);
        const u16x8 x5 = *(const u16x8*)(g + (size_t)s5*64 + c8);
        const u16x8 x6 = *(const u16x8*)(g + (size_t)s6*64 + c8);
        const u16x8 x7 = *(const u16x8*)(g + (size_t)s7*64 + c8);
        #pragma unroll
        for (int j = 0; j < 8; ++j){
            float a = fmaf(bf2f(x0[j]), dv0, fmaf(bf2f(x1[j]), dv1, fmaf(bf2f(x2[j]), dv2, bf2f(x3[j]) * dv3)));
            float c = fmaf(bf2f(x4[j]), dv4, fmaf(bf2f(x5[j]), dv5, fmaf(bf2f(x6[j]), dv6, bf2f(x7[j]) * dv7)));
            acc[j] += a + c;
        }
    }
    for (; i + 4 <= cnt; i += 4){
        const int s0 = csr_src[beg+i+0]; const int s1 = csr_src[beg+i+1];
        const int s2 = csr_src[beg+i+2]; const int s3 = csr_src[beg+i+3];
        const float dv0 = dinv[s0]; const float dv1 = dinv[s1];
        const float dv2 = dinv[s2]; const float dv3 = dinv[s3];
        const u16x8 x0 = *(const u16x8*)(g + (size_t)s0*64 + c8);
        const u16x8 x1 = *(const u16x8*)(g + (size_t)s1*64 + c8);
        const u16x8 x2 = *(const u16x8*)(g + (size_t)s2*64 + c8);
        const u16x8 x3 = *(const u16x8*)(g + (size_t)s3*64 + c8);
        #pragma unroll
        for (int j = 0; j < 8; ++j)
            acc[j] += fmaf(bf2f(x0[j]), dv0, fmaf(bf2f(x1[j]), dv1, fmaf(bf2f(x2[j]), dv2, bf2f(x3[j]) * dv3)));
    }
    for (; i < cnt; ++i){
        const int s0 = csr_src[beg+i];
        const float dv0 = dinv[s0];
        const u16x8 x0 = *(const u16x8*)(g + (size_t)s0*64 + c8);
        #pragma unroll
        for (int j = 0; j < 8; ++j) acc[j] = fmaf(bf2f(x0[j]), dv0, acc[j]);
    }
}

// ---------------- fused: aggregate layer 1 + gemm layer 2 (MFMA) -> G2 bf16 ----------------
__global__ __launch_bounds__(256) void hg_agg_gemm2(const unsigned short* __restrict__ gU, const unsigned short* __restrict__ gI,
                                                    const int* __restrict__ csrU, const int* __restrict__ csrI,
                                                    const int* __restrict__ rowptrU, const int* __restrict__ rowptrI,
                                                    const float* __restrict__ dinvU, const float* __restrict__ dinvI,
                                                    const float* __restrict__ bU, const float* __restrict__ bI,
                                                    const unsigned short* __restrict__ Bhi, const unsigned short* __restrict__ Blo,
                                                    unsigned short* __restrict__ G2U, unsigned short* __restrict__ G2I,
                                                    int NU, int NI, int nbU){
    __shared__ float hrow[32*68];
    const int type = ((int)blockIdx.x >= nbU);
    const int blk  = type ? blockIdx.x - nbU : blockIdx.x;
    const unsigned short* g = type ? gI : gU;
    const int* csr_src = type ? csrI : csrU;
    const int* rowptr  = type ? rowptrI : rowptrU;
    const float* dinv  = type ? dinvI : dinvU;
    const float* b     = type ? bI : bU;
    unsigned short* G2 = type ? G2I : G2U;
    const int N        = type ? NI : NU;
    const unsigned short* Bh = Bhi + (type ? 20480 : 16384);
    const unsigned short* Bl = Blo + (type ? 20480 : 16384);

    const int t = threadIdx.x;
    const int nodeLocal = t >> 3;
    const int c8 = (t & 7) << 3;
    const int v = blk*32 + nodeLocal;
    const bool ok = (v < N);

    float acc[8]; float dvv;
    gather_core(g, csr_src, rowptr, dinv, v, c8, ok, acc, dvv);

    {
        const float4 b0 = *(const float4*)(b + c8);
        const float4 b1 = *(const float4*)(b + c8 + 4);
        float r0 = ok ? fmaxf(fmaf(acc[0], dvv, b0.x), 0.f) : 0.f;
        float r1 = ok ? fmaxf(fmaf(acc[1], dvv, b0.y), 0.f) : 0.f;
        float r2 = ok ? fmaxf(fmaf(acc[2], dvv, b0.z), 0.f) : 0.f;
        float r3 = ok ? fmaxf(fmaf(acc[3], dvv, b0.w), 0.f) : 0.f;
        float r4 = ok ? fmaxf(fmaf(acc[4], dvv, b1.x), 0.f) : 0.f;
        float r5 = ok ? fmaxf(fmaf(acc[5], dvv, b1.y), 0.f) : 0.f;
        float r6 = ok ? fmaxf(fmaf(acc[6], dvv, b1.z), 0.f) : 0.f;
        float r7 = ok ? fmaxf(fmaf(acc[7], dvv, b1.w), 0.f) : 0.f;
        float* hr = hrow + nodeLocal*68 + c8;
        hr[0]=r0; hr[1]=r1; hr[2]=r2; hr[3]=r3; hr[4]=r4; hr[5]=r5; hr[6]=r6; hr[7]=r7;
    }
    __syncthreads();

    const int l  = t & 63;
    const int wv = t >> 6;
    const int rbase  = (wv & 1) * 16;
    const int ctbase = (wv >> 1) * 2;

    f32x4 acc2[2];
    acc2[0] = (f32x4){0.f,0.f,0.f,0.f};
    acc2[1] = (f32x4){0.f,0.f,0.f,0.f};

    const int arow = rbase + (l & 15);
    const int kg   = (l >> 4) * 8;
    #pragma unroll
    for (int ks = 0; ks < 2; ++ks){
        const float* hr = hrow + arow*68 + ks*32 + kg;
        const float4 a = *(const float4*)(hr);
        const float4 c = *(const float4*)(hr + 4);
        float xv[8] = {a.x,a.y,a.z,a.w,c.x,c.y,c.z,c.w};
        bf16x8 ahi, alo;
        #pragma unroll
        for (int j = 0; j < 8; ++j){
            const unsigned short h = f2bf(xv[j]);
            ahi[j] = (short)h;
            alo[j] = (short)f2bf(xv[j] - bf2f(h));
        }
        #pragma unroll
        for (int ct = 0; ct < 2; ++ct){
            const int slot = (ks*4 + ctbase + ct)*64 + l;
            const bf16x8 bhi = *(const bf16x8*)(Bh + (size_t)slot*8);
            const bf16x8 blo = *(const bf16x8*)(Bl + (size_t)slot*8);
            acc2[ct] = __builtin_amdgcn_mfma_f32_16x16x32_bf16(ahi, bhi, acc2[ct], 0, 0, 0);
            acc2[ct] = __builtin_amdgcn_mfma_f32_16x16x32_bf16(alo, bhi, acc2[ct], 0, 0, 0);
            acc2[ct] = __builtin_amdgcn_mfma_f32_16x16x32_bf16(ahi, blo, acc2[ct], 0, 0, 0);
        }
    }

    const int orow0 = rbase + (l >> 4)*4;
    const int ocol  = l & 15;
    #pragma unroll
    for (int r = 0; r < 4; ++r){
        const int gv = blk*32 + orow0 + r;
        if (gv < N){
            #pragma unroll
            for (int ct = 0; ct < 2; ++ct)
                G2[(size_t)gv*64 + (ctbase + ct)*16 + ocol] = f2bf(acc2[ct][r]);
        }
    }
}

// ---------------- aggregate layer 2 + fused head ----------------
__global__ __launch_bounds__(256) void hg_agghead(const unsigned short* __restrict__ gU, const unsigned short* __restrict__ gI,
                                                  const int* __restrict__ csrU, const int* __restrict__ csrI,
                                                  const int* __restrict__ rowptrU, const int* __restrict__ rowptrI,
                                                  const float* __restrict__ dinvU, const float* __restrict__ dinvI,
                                                  const float* __restrict__ bU, const float* __restrict__ bI,
                                                  const float* __restrict__ WlU, const float* __restrict__ WlI,
                                                  const float* __restrict__ blU, const float* __restrict__ blI,
                                                  float* __restrict__ outU, float* __restrict__ outI,
                                                  int NU, int NI, int nbU){
    const int type = ((int)blockIdx.x >= nbU);
    const int blk  = type ? blockIdx.x - nbU : blockIdx.x;
    const unsigned short* g = type ? gI : gU;
    const int* csr_src = type ? csrI : csrU;
    const int* rowptr  = type ? rowptrI : rowptrU;
    const float* dinv  = type ? dinvI : dinvU;
    const float* b     = type ? bI : bU;
    const float* Wl    = type ? WlI : WlU;
    const float* bl    = type ? blI : blU;
    float* outp        = type ? outI : outU;
    const int N        = type ? NI : NU;

    const int t = threadIdx.x;
    const int nodeLocal = t >> 3;
    const int c8 = (t & 7) << 3;
    const int v = blk*32 + nodeLocal;
    const bool ok = (v < N);

    float acc[8]; float dvv;
    gather_core(g, csr_src, rowptr, dinv, v, c8, ok, acc, dvv);

    float r[8];
    {
        const float4 b0 = *(const float4*)(b + c8);
        const float4 b1 = *(const float4*)(b + c8 + 4);
        r[0] = fmaxf(fmaf(acc[0], dvv, b0.x), 0.f);
        r[1] = fmaxf(fmaf(acc[1], dvv, b0.y), 0.f);
        r[2] = fmaxf(fmaf(acc[2], dvv, b0.z), 0.f);
        r[3] = fmaxf(fmaf(acc[3], dvv, b0.w), 0.f);
        r[4] = fmaxf(fmaf(acc[4], dvv, b1.x), 0.f);
        r[5] = fmaxf(fmaf(acc[5], dvv, b1.y), 0.f);
        r[6] = fmaxf(fmaf(acc[6], dvv, b1.z), 0.f);
        r[7] = fmaxf(fmaf(acc[7], dvv, b1.w), 0.f);
    }

    float p0 = 0.f, p1 = 0.f;
    #pragma unroll
    for (int j = 0; j < 8; ++j){
        const float2 wl = *(const float2*)(Wl + (size_t)(c8 + j)*2);
        p0 = fmaf(r[j], wl.x, p0);
        p1 = fmaf(r[j], wl.y, p1);
    }
    p0 += __shfl_xor(p0, 1); p1 += __shfl_xor(p1, 1);
    p0 += __shfl_xor(p0, 2); p1 += __shfl_xor(p1, 2);
    p0 += __shfl_xor(p0, 4); p1 += __shfl_xor(p1, 4);
    if (ok && (t & 7) == 0){
        float2 o; o.x = p0 + bl[0]; o.y = p1 + bl[1];
        *(float2*)(outp + (size_t)v*2) = o;
    }
}

extern "C" void kernel_launch(void* const* d_in, const int* in_sizes, int n_in,
                              void* d_out, int out_size, void* d_ws, size_t ws_size,
                              hipStream_t stream) {
    const float* x_user = (const float*)d_in[0];
    const float* x_item = (const float*)d_in[1];
    const int*  ei_user = (const int*)d_in[2];
    const int*  ei_item = (const int*)d_in[3];
    const float* W1_user = (const float*)d_in[4];
    const float* b1_user = (const float*)d_in[5];
    const float* W1_item = (const float*)d_in[6];
    const float* b1_item = (const float*)d_in[7];
    const float* W2_user = (const float*)d_in[8];
    const float* b2_user = (const float*)d_in[9];
    const float* W2_item = (const float*)d_in[10];
    const float* b2_item = (const float*)d_in[11];
    const float* Wl_user = (const float*)d_in[12];
    const float* bl_user = (const float*)d_in[13];
    const float* Wl_item = (const float*)d_in[14];
    const float* bl_item = (const float*)d_in[15];

    const int NU = in_sizes[0] / 128;
    const int NI = in_sizes[1] / 128;
    const int EU = in_sizes[2] / 2;
    const int EI = in_sizes[3] / 2;
    const int NBU = CDIV(NU, NPB);
    const int NBI = CDIV(NI, NPB);
    const int NB  = (NBU > NBI) ? NBU : NBI;
    const int pbU = CDIV(EU, PCHUNK), pbI = CDIV(EI, PCHUNK);

    char* w = (char*)d_ws;
    unsigned short* GU = (unsigned short*)w;    w += (size_t)NU * 64 * sizeof(unsigned short);
    unsigned short* GI = (unsigned short*)w;    w += (size_t)NI * 64 * sizeof(unsigned short);
    unsigned short* G2U = (unsigned short*)w;   w += (size_t)NU * 64 * sizeof(unsigned short);
    unsigned short* G2I = (unsigned short*)w;   w += (size_t)NI * 64 * sizeof(unsigned short);
    float* dinvU = (float*)w;                   w += (size_t)NU * sizeof(float);
    float* dinvI = (float*)w;                   w += (size_t)NI * sizeof(float);
    int* rowptrU = (int*)w;                     w += ((size_t)NU + 1) * sizeof(int);
    int* rowptrI = (int*)w;                     w += ((size_t)NI + 1) * sizeof(int);
    int* csrU = (int*)w;                        w += (size_t)EU * sizeof(int);
    int* csrI = (int*)w;                        w += (size_t)EI * sizeof(int);
    unsigned int* bkU = (unsigned int*)w;       w += (size_t)EU * sizeof(int);
    unsigned int* bkI = (unsigned int*)w;       w += (size_t)EI * sizeof(int);
    int* chU = (int*)w;                         w += (size_t)pbU * NB * sizeof(int);
    int* chI = (int*)w;                         w += (size_t)pbI * NB * sizeof(int);
    int* bhU = (int*)w;                         w += (size_t)NB * sizeof(int);
    int* bhI = (int*)w;                         w += (size_t)NB * sizeof(int);
    int* boffU = (int*)w;                       w += ((size_t)NB + 1) * sizeof(int);
    int* boffI = (int*)w;                       w += ((size_t)NB + 1) * sizeof(int);
    unsigned short* Bhi = (unsigned short*)w;   w += (size_t)24576 * sizeof(unsigned short);
    unsigned short* Blo = (unsigned short*)w;   w += (size_t)24576 * sizeof(unsigned short);

    float* out  = (float*)d_out;
    float* outU = out;
    float* outI = out + (size_t)2 * NU;

    // gemm1 shares across links 2-5
    const int gbU = CDIV(NU, 64), gbI = CDIV(NI, 64);
    const int GB = gbU + gbI;
    const int q = GB / 4;
    const int c2 = q, c3 = q, c4 = q, c5 = GB - 3*q;

    // link1: wsplit + chist
    hg_link1<<<WSB + pbU + pbI, 256, NB*sizeof(int), stream>>>(
        W1_user, W1_item, W2_user, W2_item, Bhi, Blo,
        ei_user, ei_item, chU, chI, EU, EI, pbU, NB);

    // link2: colscan || gemm1 slice A
    hg_link2<<<2*NB + c2, 256, 0, stream>>>(
        chU, chI, bhU, bhI, pbU, pbI, NB,
        x_user, x_item, Bhi, Blo, GU, GI, NU, NI, gbU, 0);

    // link3: bscan || gemm1 slice B
    hg_link3<<<2 + c3, 256, 0, stream>>>(
        bhU, bhI, boffU, boffI, NB, EU, EI,
        x_user, x_item, Bhi, Blo, GU, GI, NU, NI, gbU, c2);

    // link4: partition || gemm1 slice C
    const size_t p5lds = (size_t)(3*NB + 256 + 2*PCHUNK) * sizeof(int);
    hg_link4<<<pbU + pbI + c4, 256, p5lds, stream>>>(
        ei_user, ei_item, chU, chI, boffU, boffI, bkU, bkI, EU, EI, pbU, pbU + pbI, NB,
        x_user, x_item, Bhi, Blo, GU, GI, NU, NI, gbU, c2 + c3);

    // link5: bucket build || gemm1 slice D
    hg_link5<<<NBU + NBI + c5, 256, 0, stream>>>(
        bkU, bkI, boffU, boffI, dinvU, dinvI, rowptrU, rowptrI, csrU, csrI,
        NU, NI, EU, EI, NBU, NBU + NBI,
        x_user, x_item, Bhi, Blo, GU, GI, gbU, c2 + c3 + c4);

    // aggregate layer 1 + gemm layer 2 fused -> G2
    const int abU = CDIV(NU, 32), abI = CDIV(NI, 32);
    hg_agg_gemm2<<<abU + abI, 256, 0, stream>>>(GU, GI, csrU, csrI, rowptrU, rowptrI,
                                                dinvU, dinvI, b1_user, b1_item,
                                                Bhi, Blo, G2U, G2I, NU, NI, abU);

    // aggregate layer 2 + fused head
    hg_agghead<<<abU + abI, 256, 0, stream>>>(G2U, G2I, csrU, csrI, rowptrU, rowptrI,
                                              dinvU, dinvI, b2_user, b2_item,
                                              Wl_user, Wl_item, bl_user, bl_item,
                                              outU, outI, NU, NI, abU);
}